// Round 2
// baseline (359.410 us; speedup 1.0000x reference)
//
#include <hip/hip_runtime.h>

#define CCH 16
#define DD 64
#define HH 96
#define WW 96
#define HW (HH*WW)
#define DHW (DD*HH*WW)
#define K_HARRIS 0.04f

#define T 8      // output tile edge
#define XT 12    // T + 4 (x halo 2)
#define GT 10    // T + 2 (gradient halo 1)

__global__ __launch_bounds__(512)
void harris_sum_kernel(const float* __restrict__ x, float* __restrict__ p) {
    __shared__ float xs[XT*XT*XT];   // 1728 floats
    __shared__ float gxs[GT*GT*GT];  // 1000 floats
    __shared__ float gys[GT*GT*GT];
    __shared__ float gzs[GT*GT*GT];
    __shared__ float red[8];

    const int tw  = blockIdx.x;      // 0..11
    const int th  = blockIdx.y;      // 0..11
    const int tzc = blockIdx.z;      // 0..127
    const int td  = tzc & 7;         // 0..7
    const int c   = tzc >> 3;        // 0..15

    const int tid = threadIdx.x;     // 0..511
    const float* xc = x + (size_t)c * DHW;

    const int d0 = td*T - 2, h0 = th*T - 2, w0 = tw*T - 2;

    // ---- stage x tile (+halo 2) into LDS, zero-padded at volume borders ----
    for (int i = tid; i < XT*XT*XT; i += 512) {
        int lw = i % XT; int r = i / XT; int lh = r % XT; int ld = r / XT;
        int gd = d0 + ld, gh = h0 + lh, gw = w0 + lw;
        float v = 0.f;
        if ((unsigned)gd < DD && (unsigned)gh < HH && (unsigned)gw < WW)
            v = xc[gd*HW + gh*WW + gw];
        xs[i] = v;
    }
    __syncthreads();

    // ---- gradients for tile + halo 1; zero at out-of-volume positions ----
    // (box filter zero-pads the product field at the volume border)
    for (int i = tid; i < GT*GT*GT; i += 512) {
        int lw = i % GT; int r = i / GT; int lh = r % GT; int ld = r / GT;
        int gd = d0 + 1 + ld, gh = h0 + 1 + lh, gw = w0 + 1 + lw;
        float gx = 0.f, gy = 0.f, gz = 0.f;
        if ((unsigned)gd < DD && (unsigned)gh < HH && (unsigned)gw < WW) {
            float zs[3][3];
            float p0 = 0.f, p2 = 0.f;
            #pragma unroll
            for (int kh = 0; kh < 3; ++kh) {
                #pragma unroll
                for (int kw = 0; kw < 3; ++kw) {
                    float a0 = xs[(ld+0)*XT*XT + (lh+kh)*XT + (lw+kw)];
                    float a1 = xs[(ld+1)*XT*XT + (lh+kh)*XT + (lw+kw)];
                    float a2 = xs[(ld+2)*XT*XT + (lh+kh)*XT + (lw+kw)];
                    zs[kh][kw] = a0 + a1 + a2;
                    p0 += a0; p2 += a2;
                }
            }
            // sobel_x plane [[-1,0,1],[-2,0,2],[-1,0,1]] replicated over depth
            gx = (zs[0][2]-zs[0][0]) + 2.f*(zs[1][2]-zs[1][0]) + (zs[2][2]-zs[2][0]);
            // sobel_y plane [[-1,-2,-1],[0,0,0],[1,2,1]] replicated over depth
            gy = (zs[2][0]-zs[0][0]) + 2.f*(zs[2][1]-zs[0][1]) + (zs[2][2]-zs[0][2]);
            // sobel_z: -ones(d=0), zeros, +ones(d=2)
            gz = p2 - p0;
        }
        gxs[i] = gx; gys[i] = gy; gzs[i] = gz;
    }
    __syncthreads();

    // ---- 27-tap box sum of 6 products + Harris per output voxel ----
    const int lw = tid & 7, lh = (tid >> 3) & 7, ld = tid >> 6;
    float sxx=0.f, syy=0.f, szz=0.f, sxy=0.f, sxz=0.f, syz=0.f;
    #pragma unroll
    for (int nd = 0; nd < 3; ++nd) {
        #pragma unroll
        for (int nh = 0; nh < 3; ++nh) {
            #pragma unroll
            for (int nw = 0; nw < 3; ++nw) {
                int gi = (ld+nd)*GT*GT + (lh+nh)*GT + (lw+nw);
                float gx = gxs[gi], gy = gys[gi], gz = gzs[gi];
                sxx += gx*gx; syy += gy*gy; szz += gz*gz;
                sxy += gx*gy; sxz += gx*gz; syz += gy*gz;
            }
        }
    }
    const float inv27 = 1.f/27.f;
    sxx*=inv27; syy*=inv27; szz*=inv27; sxy*=inv27; sxz*=inv27; syz*=inv27;
    float det = sxx*(syy*szz - syz*syz)
              - sxy*(sxy*szz - syz*sxz)
              + sxz*(sxy*syz - syy*sxz);
    float tr = sxx + syy + szz;
    float harris = det - K_HARRIS * tr * tr;

    // ---- block reduction: wave shuffle then cross-wave via LDS ----
    #pragma unroll
    for (int off = 32; off > 0; off >>= 1)
        harris += __shfl_down(harris, off, 64);
    const int lane = tid & 63, wv = tid >> 6;
    if (lane == 0) red[wv] = harris;
    __syncthreads();
    if (tid == 0) {
        float s = 0.f;
        #pragma unroll
        for (int i = 0; i < 8; ++i) s += red[i];
        atomicAdd(&p[c], s);
    }
}

__global__ void topk_kernel(const float* __restrict__ p, int* __restrict__ idx) {
    if (threadIdx.x == 0) {
        float v[CCH];
        #pragma unroll
        for (int i = 0; i < CCH; ++i) v[i] = p[i];
        bool used[CCH];
        #pragma unroll
        for (int i = 0; i < CCH; ++i) used[i] = false;
        for (int j = 0; j < 8; ++j) {
            int best = 0; float bv = -__builtin_inff();
            for (int i = 0; i < CCH; ++i) {
                if (!used[i] && v[i] > bv) { bv = v[i]; best = i; }  // strict >: lowest index wins ties (lax.top_k stable)
            }
            used[best] = true;
            idx[j] = best;
        }
    }
}

__global__ __launch_bounds__(256)
void gather_kernel(const float* __restrict__ x, const int* __restrict__ idx,
                   float4* __restrict__ out) {
    const int ch4 = DHW / 4;                       // 147456
    const int j   = blockIdx.y;                    // 0..7
    const int pos = blockIdx.x * 256 + threadIdx.x; // < ch4 (576*256 exact)
    const int cidx = idx[j];
    const float4* src = (const float4*)(x + (size_t)cidx * DHW);
    out[(size_t)j * ch4 + pos] = src[pos];
}

extern "C" void kernel_launch(void* const* d_in, const int* in_sizes, int n_in,
                              void* d_out, int out_size, void* d_ws, size_t ws_size,
                              hipStream_t stream) {
    const float* x = (const float*)d_in[0];
    float4* out = reinterpret_cast<float4*>(d_out);
    float* p   = (float*)d_ws;                       // 16 floats
    int*   idx = (int*)((char*)d_ws + 64);           // 8 ints

    (void)hipMemsetAsync(d_ws, 0, 64, stream);       // zero p[] (ws is poisoned)

    dim3 g1(WW/T, HH/T, (DD/T) * CCH);               // (12, 12, 128)
    harris_sum_kernel<<<g1, 512, 0, stream>>>(x, p);

    topk_kernel<<<1, 64, 0, stream>>>(p, idx);

    dim3 g3((DHW/4)/256, 8, 1);                      // (576, 8)
    gather_kernel<<<g3, 256, 0, stream>>>(x, idx, out);
}

// Round 3
// 193.065 us; speedup vs baseline: 1.8616x; 1.8616x over previous
//
#include <hip/hip_runtime.h>

#define CCH 16
#define DD 64
#define HH 96
#define WW 96
#define HW (HH*WW)
#define DHW (DD*HH*WW)
#define K_HARRIS 0.04f

#define TS 16   // site tile edge (16x16 threads)
#define OT 12   // output tile edge (inner 12x12)

// Fully-separable depth-sweep Harris:
//  gx = [1,2,1]_h (x) [-1,0,1]_w (x) [1,1,1]_d
//  gy = [-1,0,1]_h (x) [1,2,1]_w (x) [1,1,1]_d
//  gz = [1,1,1]_h (x) [1,1,1]_w (x) [-1,0,1]_d
//  box = [1,1,1]^3 / 27
// Per d-slice: A = depth-3 sum of x, Dz = x(d+1)-x(d-1) (registers),
// then 4 LDS rounds (w-conv, h-conv+products, w-conv, h-conv) and a
// register rolling window over d for the final box depth-sum.
// LDS row stride 16 -> wave64 access = exactly 2 lanes/bank (free).
__global__ __launch_bounds__(256)
void harris_sum_kernel(const float* __restrict__ x, float* __restrict__ p) {
    __shared__ float sA[TS*TS], sDz[TS*TS];
    __shared__ float sSx[TS*TS], sTx[TS*TS], sTd[TS*TS];
    __shared__ float sP[6][TS*TS];
    __shared__ float sR[6][TS*TS];

    const int tid = threadIdx.x;           // 0..255
    const int lw = tid & 15, lh = tid >> 4;
    const int c  = blockIdx.z;
    const int H0 = blockIdx.y * OT, W0 = blockIdx.x * OT;
    const int gh = H0 + lh - 2, gw = W0 + lw - 2;
    const bool in_plane = ((unsigned)gh < HH) && ((unsigned)gw < WW);
    const float mask = in_plane ? 1.f : 0.f;   // zero products at out-of-volume sites
    const float* xc = x + (size_t)c * DHW;
    const int off = gh * WW + gw;              // only dereferenced when in_plane

    const bool a1 = (lw >= 1) && (lw <= 14);                      // w-conv sites
    const bool a2 = a1 && (lh >= 1) && (lh <= 14);                // gradient/product sites
    const bool a3 = (lw >= 2) && (lw <= 13) && (lh >= 1) && (lh <= 14); // product w-conv
    const bool a4 = a3 && (lh >= 2) && (lh <= 13);                // output sites

    // rolling x window (depth), prefetch 2 ahead
    float xp = 0.f, xcr = 0.f, xn = 0.f, xn2 = 0.f;
    if (in_plane) {
        xn  = xc[off];        // x(0)
        xn2 = xc[HW + off];   // x(1)
    }

    float s2m1[6], s2m2[6];
    #pragma unroll
    for (int f = 0; f < 6; ++f) { s2m1[f] = 0.f; s2m2[f] = 0.f; }
    float hacc = 0.f;
    const float inv27 = 1.f / 27.f;

    for (int e = 0; e < DD; ++e) {
        xp = xcr; xcr = xn; xn = xn2;
        xn2 = (in_plane && (e + 2) < DD) ? xc[(size_t)(e + 2) * HW + off] : 0.f;

        const float A  = xp + xcr + xn;   // depth-3 box of x at slice e
        const float Dz = xn - xp;         // depth [-1,0,1] at slice e
        sA[tid] = A; sDz[tid] = Dz;
        __syncthreads();

        float Sx = 0.f, Tx = 0.f, Td = 0.f;
        if (a1) {
            float Am = sA[tid-1],  Ap = sA[tid+1];
            float Dm = sDz[tid-1], Dp = sDz[tid+1];
            Sx = Ap - Am;             // [-1,0,1]_w on A
            Tx = Am + 2.f*A + Ap;     // [1,2,1]_w  on A
            Td = Dm + Dz + Dp;        // [1,1,1]_w  on Dz
            sSx[tid] = Sx; sTx[tid] = Tx; sTd[tid] = Td;
        }
        __syncthreads();

        float pv0=0.f,pv1=0.f,pv2=0.f,pv3=0.f,pv4=0.f,pv5=0.f;
        if (a2) {
            float sxm = sSx[tid-TS], sxp = sSx[tid+TS];
            float txm = sTx[tid-TS], txp = sTx[tid+TS];
            float tdm = sTd[tid-TS], tdp = sTd[tid+TS];
            float gx = (sxm + 2.f*Sx + sxp) * mask;  // [1,2,1]_h
            float gy = (txp - txm) * mask;           // [-1,0,1]_h
            float gz = (tdm + Td + tdp) * mask;      // [1,1,1]_h
            pv0 = gx*gx; pv1 = gy*gy; pv2 = gz*gz;
            pv3 = gx*gy; pv4 = gx*gz; pv5 = gy*gz;
            sP[0][tid]=pv0; sP[1][tid]=pv1; sP[2][tid]=pv2;
            sP[3][tid]=pv3; sP[4][tid]=pv4; sP[5][tid]=pv5;
        }
        __syncthreads();

        float rv0=0.f,rv1=0.f,rv2=0.f,rv3=0.f,rv4=0.f,rv5=0.f;
        if (a3) {
            rv0 = sP[0][tid-1] + pv0 + sP[0][tid+1]; sR[0][tid] = rv0;
            rv1 = sP[1][tid-1] + pv1 + sP[1][tid+1]; sR[1][tid] = rv1;
            rv2 = sP[2][tid-1] + pv2 + sP[2][tid+1]; sR[2][tid] = rv2;
            rv3 = sP[3][tid-1] + pv3 + sP[3][tid+1]; sR[3][tid] = rv3;
            rv4 = sP[4][tid-1] + pv4 + sP[4][tid+1]; sR[4][tid] = rv4;
            rv5 = sP[5][tid-1] + pv5 + sP[5][tid+1]; sR[5][tid] = rv5;
        }
        __syncthreads();

        if (a4) {
            float s2c0 = sR[0][tid-TS] + rv0 + sR[0][tid+TS];
            float s2c1 = sR[1][tid-TS] + rv1 + sR[1][tid+TS];
            float s2c2 = sR[2][tid-TS] + rv2 + sR[2][tid+TS];
            float s2c3 = sR[3][tid-TS] + rv3 + sR[3][tid+TS];
            float s2c4 = sR[4][tid-TS] + rv4 + sR[4][tid+TS];
            float s2c5 = sR[5][tid-TS] + rv5 + sR[5][tid+TS];
            if (e >= 1) {   // emit output slice o = e-1
                float sxx = (s2m2[0]+s2m1[0]+s2c0)*inv27;
                float syy = (s2m2[1]+s2m1[1]+s2c1)*inv27;
                float szz = (s2m2[2]+s2m1[2]+s2c2)*inv27;
                float sxy = (s2m2[3]+s2m1[3]+s2c3)*inv27;
                float sxz = (s2m2[4]+s2m1[4]+s2c4)*inv27;
                float syz = (s2m2[5]+s2m1[5]+s2c5)*inv27;
                float det = sxx*(syy*szz - syz*syz)
                          - sxy*(sxy*szz - syz*sxz)
                          + sxz*(sxy*syz - syy*sxz);
                float tr = sxx + syy + szz;
                hacc += det - K_HARRIS * tr * tr;
            }
            s2m2[0]=s2m1[0]; s2m1[0]=s2c0;
            s2m2[1]=s2m1[1]; s2m1[1]=s2c1;
            s2m2[2]=s2m1[2]; s2m1[2]=s2c2;
            s2m2[3]=s2m1[3]; s2m1[3]=s2c3;
            s2m2[4]=s2m1[4]; s2m1[4]=s2c4;
            s2m2[5]=s2m1[5]; s2m1[5]=s2c5;
        }
        // no sync needed here: next iter's writes are each guarded by the
        // barrier chain before their readers/writers touch the same array
    }

    if (a4) {   // emit last output slice o = 63 (S2(64) = 0)
        float sxx = (s2m2[0]+s2m1[0])*inv27;
        float syy = (s2m2[1]+s2m1[1])*inv27;
        float szz = (s2m2[2]+s2m1[2])*inv27;
        float sxy = (s2m2[3]+s2m1[3])*inv27;
        float sxz = (s2m2[4]+s2m1[4])*inv27;
        float syz = (s2m2[5]+s2m1[5])*inv27;
        float det = sxx*(syy*szz - syz*syz)
                  - sxy*(sxy*szz - syz*sxz)
                  + sxz*(sxy*syz - syy*sxz);
        float tr = sxx + syy + szz;
        hacc += det - K_HARRIS * tr * tr;
    }

    // block reduction -> one atomic per block
    #pragma unroll
    for (int o = 32; o > 0; o >>= 1) hacc += __shfl_down(hacc, o, 64);
    __syncthreads();
    if ((tid & 63) == 0) sA[tid >> 6] = hacc;
    __syncthreads();
    if (tid == 0) atomicAdd(&p[c], sA[0] + sA[1] + sA[2] + sA[3]);
}

// top-k selection fused into the gather (every block recomputes the tiny
// 16->8 selection from the same finalized p[] -> consistent across blocks)
__global__ __launch_bounds__(256)
void gather_topk_kernel(const float* __restrict__ x, const float* __restrict__ p,
                        float4* __restrict__ out) {
    __shared__ int sidx[8];
    if (threadIdx.x == 0) {
        float v[CCH]; bool used[CCH];
        #pragma unroll
        for (int i = 0; i < CCH; ++i) { v[i] = p[i]; used[i] = false; }
        for (int j = 0; j < 8; ++j) {
            int best = 0; float bv = -__builtin_inff();
            for (int i = 0; i < CCH; ++i)
                if (!used[i] && v[i] > bv) { bv = v[i]; best = i; } // strict >: stable ties
            used[best] = true;
            sidx[j] = best;
        }
    }
    __syncthreads();
    const int ch4 = DHW / 4;                         // 147456
    const int j   = blockIdx.y;                      // 0..7
    const int pos = blockIdx.x * 256 + threadIdx.x;  // 576*256 == ch4 exact
    const int cidx = sidx[j];
    const float4* src = (const float4*)(x + (size_t)cidx * DHW);
    out[(size_t)j * ch4 + pos] = src[pos];
}

extern "C" void kernel_launch(void* const* d_in, const int* in_sizes, int n_in,
                              void* d_out, int out_size, void* d_ws, size_t ws_size,
                              hipStream_t stream) {
    const float* x = (const float*)d_in[0];
    float4* out = reinterpret_cast<float4*>(d_out);
    float* p = (float*)d_ws;                         // 16 floats

    (void)hipMemsetAsync(d_ws, 0, 64, stream);       // zero p[]

    dim3 g1(WW/OT, HH/OT, CCH);                      // (8, 8, 16) = 1024 blocks
    harris_sum_kernel<<<g1, 256, 0, stream>>>(x, p);

    dim3 g2((DHW/4)/256, 8, 1);                      // (576, 8)
    gather_topk_kernel<<<g2, 256, 0, stream>>>(x, p, out);
}

// Round 5
// 174.124 us; speedup vs baseline: 2.0641x; 1.1088x over previous
//
#include <hip/hip_runtime.h>

#define CCH 16
#define DD 64
#define HH 96
#define WW 96
#define HW (HH*WW)
#define DHW (DD*HH*WW)   // 589824
#define CH4 (DHW/4)      // 147456
#define NTH 384
#define KTR 1.08f                 // 27 * k_harris
#define INV27C (1.f/19683.f)      // 27^-3

// DPP row16 shifts: thread layout is lh-fast (lh = tid & 15), so a DPP row of
// 16 lanes == one h-column; bound_ctrl=true zero-fills at row ends (the filled
// sites only feed non-emitted outputs). Harris is invariant to an up/down swap
// (all terms have even degree in each gradient; a swap only flips gy's sign).
__device__ __forceinline__ float dpp_up(float v) {   // lane lh <- lh-1
    return __int_as_float(__builtin_amdgcn_update_dpp(
        0, __float_as_int(v), 0x111 /*row_shr:1*/, 0xF, 0xF, true));
}
__device__ __forceinline__ float dpp_dn(float v) {   // lane lh <- lh+1
    return __int_as_float(__builtin_amdgcn_update_dpp(
        0, __float_as_int(v), 0x101 /*row_shl:1*/, 0xF, 0xF, true));
}

__device__ __forceinline__ void load4(float v[4], const float* __restrict__ xc,
                                      int e, int woff, bool rowok) {
    if (rowok && (unsigned)e < DD) {
        const float4 t = *(const float4*)(xc + (size_t)e * HW + woff);
        v[0] = t.x; v[1] = t.y; v[2] = t.z; v[3] = t.w;
    } else {
        v[0] = v[1] = v[2] = v[3] = 0.f;
    }
}

// Depth-sweep separable Harris, thread owns 4 consecutive w sites (float4);
// w-convs register-internal + LDS edge exchange; h-convs via DPP (VALU pipe).
// Block: 384 threads = 16 lh x 24 lc covers full W=96, h-tile 12 (+2 halo).
__global__ __launch_bounds__(NTH, 3)
void harris_sum_kernel(const float* __restrict__ x, float* __restrict__ p) {
    __shared__ float eA[4][NTH];    // A.x, A.w, Dz.x, Dz.w edges
    __shared__ float eP[12][NTH];   // P[f].x, P[f].w edges
    __shared__ float red[8];

    const int tid = threadIdx.x;
    const int lh = tid & 15, lc = tid >> 4;
    const int c  = blockIdx.z;
    const int H0 = blockIdx.x * 12;
    const int o0 = blockIdx.y * 16;
    const int gh = H0 + lh - 2;
    const bool rowok = ((unsigned)gh < HH);
    const float mask = rowok ? 1.f : 0.f;   // zero products at OOB rows (box zero-pad)
    const float* xc = x + (size_t)c * DHW;
    const int woff = gh * WW + (lc << 2);

    // rolling x window: xp=x(e-1), xm=x(e), xn=x(e+1)
    float xp[4], xm[4], xn[4];
    load4(xp, xc, o0 - 2, woff, rowok);
    load4(xm, xc, o0 - 1, woff, rowok);
    load4(xn, xc, o0,     woff, rowok);

    float s2m1[6][4], s2m2[6][4];
    #pragma unroll
    for (int f = 0; f < 6; ++f)
        #pragma unroll
        for (int i = 0; i < 4; ++i) { s2m1[f][i] = 0.f; s2m2[f][i] = 0.f; }
    float hs = 0.f;

    for (int e = o0 - 1; e <= o0 + 16; ++e) {
        float xf[4];
        load4(xf, xc, e + 2, woff, rowok);   // prefetch next slice

        float s2c[6][4];
        if ((unsigned)e < DD) {              // block-uniform branch
            float A[4], Dz[4];
            #pragma unroll
            for (int i = 0; i < 4; ++i) {
                A[i]  = xp[i] + xm[i] + xn[i];   // depth [1,1,1]
                Dz[i] = xn[i] - xp[i];           // depth [-1,0,1]
            }
            eA[0][tid] = A[0];  eA[1][tid] = A[3];
            eA[2][tid] = Dz[0]; eA[3][tid] = Dz[3];
            __syncthreads();
            float Alw = (lc > 0)  ? eA[1][tid - 16] : 0.f;
            float Dlw = (lc > 0)  ? eA[3][tid - 16] : 0.f;
            float Arx = (lc < 23) ? eA[0][tid + 16] : 0.f;
            float Drx = (lc < 23) ? eA[2][tid + 16] : 0.f;
            const float Al[4] = {Alw, A[0], A[1], A[2]};
            const float Ar[4] = {A[1], A[2], A[3], Arx};
            const float Dl[4] = {Dlw, Dz[0], Dz[1], Dz[2]};
            const float Dr[4] = {Dz[1], Dz[2], Dz[3], Drx};

            float P[6][4];
            #pragma unroll
            for (int i = 0; i < 4; ++i) {
                float Sx = Ar[i] - Al[i];               // w [-1,0,1] on A
                float Tx = Al[i] + 2.f*A[i] + Ar[i];    // w [1,2,1]  on A
                float Td = Dl[i] + Dz[i] + Dr[i];       // w [1,1,1]  on Dz
                float gx = (dpp_up(Sx) + 2.f*Sx + dpp_dn(Sx)) * mask;  // h [1,2,1]
                float gy = (dpp_dn(Tx) - dpp_up(Tx)) * mask;           // h [-1,0,1]
                float gz = (dpp_up(Td) + Td + dpp_dn(Td)) * mask;      // h [1,1,1]
                P[0][i] = gx*gx; P[1][i] = gy*gy; P[2][i] = gz*gz;
                P[3][i] = gx*gy; P[4][i] = gx*gz; P[5][i] = gy*gz;
            }
            #pragma unroll
            for (int f = 0; f < 6; ++f) { eP[2*f][tid] = P[f][0]; eP[2*f+1][tid] = P[f][3]; }
            __syncthreads();
            #pragma unroll
            for (int f = 0; f < 6; ++f) {
                float pl = (lc > 0)  ? eP[2*f+1][tid - 16] : 0.f;
                float pr = (lc < 23) ? eP[2*f][tid + 16]   : 0.f;
                float R0 = pl      + P[f][0] + P[f][1];
                float R1 = P[f][0] + P[f][1] + P[f][2];
                float R2 = P[f][1] + P[f][2] + P[f][3];
                float R3 = P[f][2] + P[f][3] + pr;
                s2c[f][0] = dpp_up(R0) + R0 + dpp_dn(R0);   // h [1,1,1]
                s2c[f][1] = dpp_up(R1) + R1 + dpp_dn(R1);
                s2c[f][2] = dpp_up(R2) + R2 + dpp_dn(R2);
                s2c[f][3] = dpp_up(R3) + R3 + dpp_dn(R3);
            }
        } else {
            #pragma unroll
            for (int f = 0; f < 6; ++f)
                #pragma unroll
                for (int i = 0; i < 4; ++i) s2c[f][i] = 0.f;
        }

        if (e > o0 && lh >= 2 && lh <= 13) {   // emit output slice o = e-1
            #pragma unroll
            for (int i = 0; i < 4; ++i) {
                float sxx = s2m2[0][i] + s2m1[0][i] + s2c[0][i];
                float syy = s2m2[1][i] + s2m1[1][i] + s2c[1][i];
                float szz = s2m2[2][i] + s2m1[2][i] + s2c[2][i];
                float sxy = s2m2[3][i] + s2m1[3][i] + s2c[3][i];
                float sxz = s2m2[4][i] + s2m1[4][i] + s2c[4][i];
                float syz = s2m2[5][i] + s2m1[5][i] + s2c[5][i];
                float det = sxx*(syy*szz - syz*syz)
                          - sxy*(sxy*szz - syz*sxz)
                          + sxz*(sxy*syz - syy*sxz);
                float tr = sxx + syy + szz;
                hs += det - KTR * tr * tr;   // unscaled; *27^-3 once at the end
            }
        }
        #pragma unroll
        for (int f = 0; f < 6; ++f)
            #pragma unroll
            for (int i = 0; i < 4; ++i) { s2m2[f][i] = s2m1[f][i]; s2m1[f][i] = s2c[f][i]; }
        #pragma unroll
        for (int i = 0; i < 4; ++i) { xp[i] = xm[i]; xm[i] = xn[i]; xn[i] = xf[i]; }
    }

    // block reduce -> one atomic per block
    #pragma unroll
    for (int o = 32; o > 0; o >>= 1) hs += __shfl_down(hs, o, 64);
    if ((tid & 63) == 0) red[tid >> 6] = hs;
    __syncthreads();
    if (tid == 0) {
        float tot = (red[0] + red[1] + red[2] + red[3] + red[4] + red[5]) * INV27C;
        atomicAdd(&p[c], tot);
    }
}

// top-k fused into gather: every block recomputes the tiny 16->8 selection
// from the same finalized p[] (kernel-boundary visibility) -> consistent.
__global__ __launch_bounds__(256)
void gather_topk_kernel(const float* __restrict__ x, const float* __restrict__ p,
                        float4* __restrict__ out) {
    __shared__ int sidx[8];
    if (threadIdx.x == 0) {
        float v[CCH]; bool used[CCH];
        #pragma unroll
        for (int i = 0; i < CCH; ++i) { v[i] = p[i]; used[i] = false; }
        for (int j = 0; j < 8; ++j) {
            int best = 0; float bv = -__builtin_inff();
            for (int i = 0; i < CCH; ++i)
                if (!used[i] && v[i] > bv) { bv = v[i]; best = i; } // strict >: stable ties
            used[best] = true;
            sidx[j] = best;
        }
    }
    __syncthreads();
    const int j   = blockIdx.y;                      // 0..7
    const int pos = blockIdx.x * 256 + threadIdx.x;  // 576*256 == CH4 exact
    const int cidx = sidx[j];
    const float4* src = (const float4*)(x + (size_t)cidx * DHW);
    out[(size_t)j * CH4 + pos] = src[pos];
}

extern "C" void kernel_launch(void* const* d_in, const int* in_sizes, int n_in,
                              void* d_out, int out_size, void* d_ws, size_t ws_size,
                              hipStream_t stream) {
    const float* x = (const float*)d_in[0];
    float4* out = reinterpret_cast<float4*>(d_out);
    float* p = (float*)d_ws;                         // 16 floats

    (void)hipMemsetAsync(d_ws, 0, 64, stream);       // zero p[]

    dim3 g1(8, 4, CCH);                              // 512 blocks
    harris_sum_kernel<<<g1, NTH, 0, stream>>>(x, p);

    dim3 g2(CH4 / 256, 8, 1);                        // (576, 8)
    gather_topk_kernel<<<g2, 256, 0, stream>>>(x, p, out);
}